// Round 9
// baseline (1374.783 us; speedup 1.0000x reference)
//
#include <hip/hip_runtime.h>

// LowRankKVCache: out = X @ Vt^T @ Vt where Vt = top-64 eigenvectors of X^T X.
// 64 independent 2048x128 fp32 matrices (B*H = 4*16).
//
// Round 11: odd-even always-swap Jacobi (verified schedule of R1/R7), 4
// register columns per group (32 groups x 16 lanes), with:
//  (1) ONE barrier per round: cross pairs (4g+3,4g+4) are computed
//      REDUNDANTLY by both neighbor groups (bitwise-identical inputs ->
//      identical rotation); each keeps only its own half. No handback.
//  (2) Double-buffered transit regions (ping-pong on round parity) make the
//      single barrier race-free.
//  (3) NSWEEP=7 (R8's 6-sweep failure showed no margin at 6) + exact norm
//      refresh every sweep (kills carried-norm drift compounding).
// Norm-carrying within a sweep: app' = app - tv*apq, aqq' = aqq + tv*apq.
//
// ws layout (bytes):
//   [0, 4M)        G      (64 x 128x128 f32)   -- dead after jacobi
//   [4M, 8M)       Vfull  (64 x 128x128 f32)   -- dead after select_k
//   [8M, 8M+32K)   normg  (64 x 128 f32)       -- dead after select_k
//   [32M, 34M)     Vt     (64 x 64x128 f32)
//   [0, 32M)       W      (64 x 2048x64 f32)   -- overlays dead G/Vfull/normg
// total requirement: 34 MB of d_ws.

#define NM 64
#define SEQ 2048
#define DD 128
#define RR 64
#define NSWEEP 7

#define OFF_VFULL (4194304ULL)
#define OFF_NORM  (8388608ULL)
#define OFF_VT    (33554432ULL)

__device__ __forceinline__ float dot4(float4 a, float4 b) {
  return a.x * b.x + a.y * b.y + a.z * b.z + a.w * b.w;
}

// DPP butterfly add (VALU pipe). Ctrls: 0xB1 quad xor1, 0x4E quad xor2,
// 0x141 row_half_mirror, 0x140 row_mirror -- all within 16-lane rows.
template <int CTRL>
__device__ __forceinline__ float dpp_add(float x) {
  int y = __builtin_amdgcn_update_dpp(0, __float_as_int(x), CTRL, 0xf, 0xf, true);
  return x + __int_as_float(y);
}
__device__ __forceinline__ float red16(float x) {  // sum over aligned 16 lanes
  x = dpp_add<0xB1>(x);
  x = dpp_add<0x4E>(x);
  x = dpp_add<0x141>(x);
  x = dpp_add<0x140>(x);
  return x;
}

// Branchless Jacobi rotation from (app, apq, aqq). Converged pairs get exact
// identity (c=1, s=0, tv=0); caller always swaps. tv drives the analytic
// norm update: app' = app - tv*apq, aqq' = aqq + tv*apq (trace-preserving).
__device__ __forceinline__ void jrot(float app, float apq, float aqq,
                                     float& c, float& s, float& tv) {
  bool ok = apq * apq > 1e-9f * app * aqq;
  float ap = ok ? apq : 1.f;            // NaN-safe denominator
  float tau = (aqq - app) / (2.f * ap);
  float t = 1.f / (fabsf(tau) + sqrtf(1.f + tau * tau));
  t = tau < 0.f ? -t : t;
  float cc = 1.f / sqrtf(1.f + t * t);
  float ss = t * cc;
  c = ok ? cc : 1.f;
  s = ok ? ss : 0.f;
  tv = ok ? t : 0.f;
}

__device__ __forceinline__ void rot4(float c, float s, float4 p, float4 q,
                                     float4& np, float4& nq) {
  np.x = c * p.x - s * q.x;  nq.x = s * p.x + c * q.x;
  np.y = c * p.y - s * q.y;  nq.y = s * p.y + c * q.y;
  np.z = c * p.z - s * q.z;  nq.z = s * p.z + c * q.z;
  np.w = c * p.w - s * q.w;  nq.w = s * p.w + c * q.w;
}
__device__ __forceinline__ float4 np4(float c, float s, float4 p, float4 q) {
  return make_float4(c * p.x - s * q.x, c * p.y - s * q.y,
                     c * p.z - s * q.z, c * p.w - s * q.w);
}
__device__ __forceinline__ float4 nq4(float c, float s, float4 p, float4 q) {
  return make_float4(s * p.x + c * q.x, s * p.y + c * q.y,
                     s * p.z + c * q.z, s * p.w + c * q.w);
}

// Rotate register-resident pair (slotP=P, slotQ=Q), always-swap, with
// carried-norm update. Each column is 2 float4 per lane (16 lanes/column).
__device__ __forceinline__ void rot2pair(float4* P, float4* Q,
                                         float& npn, float& nqn) {
  float apq = red16(dot4(P[0], Q[0]) + dot4(P[1], Q[1]));
  float c, s, tv;
  jrot(npn, apq, nqn, c, s, tv);
  float4 a, b;
  rot4(c, s, P[0], Q[0], a, b); P[0] = b; Q[0] = a;  // slotP<-nq, slotQ<-np
  rot4(c, s, P[1], Q[1], a, b); P[1] = b; Q[1] = a;
  float t = npn;
  npn = nqn + tv * apq;  // norm(nq)
  nqn = t - tv * apq;    // norm(np)
}

// ---------------- K1: Gram G[m] = X[m]^T X[m] ----------------
__global__ __launch_bounds__(256) void gram_k(const float* __restrict__ X,
                                              float* __restrict__ G) {
  const int m = blockIdx.y;
  const int r0 = blockIdx.x * 32;  // G row tile (== X column tile)
  const int tid = threadIdx.x;
  __shared__ __align__(16) float Xs[64][128];  // 32 KB
  const float* Xm = X + (size_t)m * SEQ * DD;
  const int ti = tid >> 5;  // 0..7  -> G rows r0+4ti..+3
  const int tj = tid & 31;  // 0..31 -> G cols 4tj..+3
  float acc[4][4];
#pragma unroll
  for (int a = 0; a < 4; ++a)
#pragma unroll
    for (int b = 0; b < 4; ++b) acc[a][b] = 0.f;

  for (int s0 = 0; s0 < SEQ; s0 += 64) {
    __syncthreads();
    for (int t = tid; t < 2048; t += 256) {  // 64 rows x 32 float4
      int s = t >> 5, c4 = t & 31;
      *(float4*)&Xs[s][c4 * 4] =
          *(const float4*)&Xm[(size_t)(s0 + s) * DD + c4 * 4];
    }
    __syncthreads();
#pragma unroll 4
    for (int s = 0; s < 64; ++s) {
      float4 av = *(const float4*)&Xs[s][r0 + 4 * ti];
      float4 bv = *(const float4*)&Xs[s][4 * tj];
      acc[0][0] += av.x * bv.x; acc[0][1] += av.x * bv.y;
      acc[0][2] += av.x * bv.z; acc[0][3] += av.x * bv.w;
      acc[1][0] += av.y * bv.x; acc[1][1] += av.y * bv.y;
      acc[1][2] += av.y * bv.z; acc[1][3] += av.y * bv.w;
      acc[2][0] += av.z * bv.x; acc[2][1] += av.z * bv.y;
      acc[2][2] += av.z * bv.z; acc[2][3] += av.z * bv.w;
      acc[3][0] += av.w * bv.x; acc[3][1] += av.w * bv.y;
      acc[3][2] += av.w * bv.z; acc[3][3] += av.w * bv.w;
    }
  }
  float* Gm = G + (size_t)m * DD * DD;
#pragma unroll
  for (int a = 0; a < 4; ++a) {
    float4 v = make_float4(acc[a][0], acc[a][1], acc[a][2], acc[a][3]);
    *(float4*)&Gm[(size_t)(r0 + 4 * ti + a) * DD + 4 * tj] = v;
  }
}

// ---------------- K2: 1-barrier odd-even Jacobi, 4 reg columns/group -------
// 512 threads = 32 groups x 16 lanes. Group g owns slots 4g..4g+3 in VGPRs
// (lane l holds float4s {l, l+16} of each column) + carried norms n0..n3.
// Transit: xch[buf][0][g] = group g's post-A c0; xch[buf][1][g] = post-A c3.
// Norms carved into the unused regions xch[buf][0][0] (group 0 publishes no
// c0): floats [1..31] = c0 norms, [64..94] = c3 norms.
__global__ __launch_bounds__(512) void jacobi1b_k(const float* __restrict__ G,
                                                  float* __restrict__ Vfull,
                                                  float* __restrict__ normg) {
  const int m = blockIdx.x;
  const int tid = threadIdx.x;
  const int g = tid >> 4;   // group 0..31
  const int l = tid & 15;   // lane in group
  __shared__ __align__(16) float4 xch[2][2][32][32];  // 64 KB exactly

  // G is symmetric: column j of G == row j of G -> transpose-free load.
  const float4* Gm4 = (const float4*)(G + (size_t)m * DD * DD);
  float4 c0[2], c1[2], c2[2], c3[2];
#pragma unroll
  for (int j = 0; j < 2; ++j) {
    c0[j] = Gm4[(size_t)(4 * g + 0) * 32 + l + 16 * j];
    c1[j] = Gm4[(size_t)(4 * g + 1) * 32 + l + 16 * j];
    c2[j] = Gm4[(size_t)(4 * g + 2) * 32 + l + 16 * j];
    c3[j] = Gm4[(size_t)(4 * g + 3) * 32 + l + 16 * j];
  }
  float n0 = red16(dot4(c0[0], c0[0]) + dot4(c0[1], c0[1]));
  float n1 = red16(dot4(c1[0], c1[0]) + dot4(c1[1], c1[1]));
  float n2 = red16(dot4(c2[0], c2[0]) + dot4(c2[1], c2[1]));
  float n3 = red16(dot4(c3[0], c3[0]) + dot4(c3[1], c3[1]));

  const bool hasR = (g < 31);  // cross pair (4g+3, 4g+4) exists
  const bool hasL = (g > 0);   // cross pair (4g-1, 4g) exists

  for (int sweep = 0; sweep < NSWEEP; ++sweep) {
#pragma unroll 1
    for (int round = 0; round < 64; ++round) {
      const int b = round & 1;
      float* nb = (float*)&xch[b][0][0][0];  // norm carve (region unused)
      // ---- A-matching: (4g,4g+1), (4g+2,4g+3) -- register-only ----
      rot2pair(c0, c1, n0, n1);
      rot2pair(c2, c3, n2, n3);
      // ---- publish boundary columns (post-A) ----
      if (hasL) {
        xch[b][0][g][l] = c0[0];
        xch[b][0][g][l + 16] = c0[1];
        if (l == 0) nb[g] = n0;
      }
      if (hasR) {
        xch[b][1][g][l] = c3[0];
        xch[b][1][g][l + 16] = c3[1];
        if (l == 0) nb[64 + g] = n3;
      }
      __syncthreads();  // the ONLY barrier per round (ping-pong buffers)
      // ---- read neighbors' boundary columns ----
      float4 rq0, rq1, lp0, lp1;
      float nrq = 0.f, nlp = 0.f;
      if (hasR) {
        rq0 = xch[b][0][g + 1][l];
        rq1 = xch[b][0][g + 1][l + 16];
        nrq = nb[g + 1];
      }
      if (hasL) {
        lp0 = xch[b][1][g - 1][l];
        lp1 = xch[b][1][g - 1][l + 16];
        nlp = nb[64 + g - 1];
      }
      // ---- middle B-pair (4g+1,4g+2): reg-only, hides the read latency ---
      rot2pair(c1, c2, n1, n2);
      // ---- cross pairs, duplicate-computed; keep own half only ----
      if (hasR) {  // pair (4g+3, 4g+4): p = my c3, q = right c0. keep nq.
        float apq = red16(dot4(c3[0], rq0) + dot4(c3[1], rq1));
        float c, s, tv;
        jrot(n3, apq, nrq, c, s, tv);
        c3[0] = nq4(c, s, c3[0], rq0);
        c3[1] = nq4(c, s, c3[1], rq1);
        n3 = nrq + tv * apq;  // norm(nq)
      }
      if (hasL) {  // pair (4g-1, 4g): p = left c3, q = my c0. keep np.
        float apq = red16(dot4(lp0, c0[0]) + dot4(lp1, c0[1]));
        float c, s, tv;
        jrot(nlp, apq, n0, c, s, tv);
        c0[0] = np4(c, s, lp0, c0[0]);
        c0[1] = np4(c, s, lp1, c0[1]);
        n0 = nlp - tv * apq;  // norm(np)
      }
      // no second barrier: next round writes the other buffer.
    }
    // ---- exact norm refresh each sweep (kills carried-norm drift) ----
    n0 = red16(dot4(c0[0], c0[0]) + dot4(c0[1], c0[1]));
    n1 = red16(dot4(c1[0], c1[0]) + dot4(c1[1], c1[1]));
    n2 = red16(dot4(c2[0], c2[0]) + dot4(c2[1], c2[1]));
    n3 = red16(dot4(c3[0], c3[0]) + dot4(c3[1], c3[1]));
  }

  // Emit all 128 (unnormalized) eigenvector candidates + exact squared
  // norms. Column order is arbitrary -- select_k ranks by norm.
  float4* V0 = (float4*)(Vfull + ((size_t)m * DD + 4 * g + 0) * DD);
  float4* V1 = (float4*)(Vfull + ((size_t)m * DD + 4 * g + 1) * DD);
  float4* V2 = (float4*)(Vfull + ((size_t)m * DD + 4 * g + 2) * DD);
  float4* V3 = (float4*)(Vfull + ((size_t)m * DD + 4 * g + 3) * DD);
#pragma unroll
  for (int j = 0; j < 2; ++j) {
    V0[l + 16 * j] = c0[j];
    V1[l + 16 * j] = c1[j];
    V2[l + 16 * j] = c2[j];
    V3[l + 16 * j] = c3[j];
  }
  if (l == 0) {
    normg[m * DD + 4 * g + 0] = n0;  // |col|^2 = lambda^2 (just refreshed)
    normg[m * DD + 4 * g + 1] = n1;
    normg[m * DD + 4 * g + 2] = n2;
    normg[m * DD + 4 * g + 3] = n3;
  }
}

// ---------------- K2b: rank-select top-64 columns, normalize -> Vt ---------
__global__ __launch_bounds__(128) void select_k(const float* __restrict__ Vfull,
                                                const float* __restrict__ normg,
                                                float* __restrict__ Vt) {
  const int m = blockIdx.x;
  const int t = threadIdx.x;  // 0..127
  __shared__ float n[DD];
  __shared__ int inv[RR];
  __shared__ float scl[RR];
  n[t] = normg[m * DD + t];
  __syncthreads();
  float nt = n[t];
  int rk = 0;
  for (int k = 0; k < DD; ++k) {
    float nk = n[k];
    rk += ((nk > nt) || (nk == nt && k < t)) ? 1 : 0;
  }
  if (rk < RR) { inv[rk] = t; scl[rk] = 1.f / sqrtf(nt); }
  __syncthreads();
  for (int r = 0; r < RR; ++r) {
    Vt[((size_t)m * RR + r) * DD + t] =
        Vfull[((size_t)m * DD + inv[r]) * DD + t] * scl[r];
  }
}

// ---------------- K4: W = X @ Vt^T  (2048x64 per matrix) -------------------
__global__ __launch_bounds__(256) void gemm1_k(const float* __restrict__ X,
                                               const float* __restrict__ Vt,
                                               float* __restrict__ W) {
  const int m = blockIdx.y;
  const int s0 = blockIdx.x * 32;
  const int tid = threadIdx.x;
  __shared__ __align__(16) float VtT[128 * 68];  // [c][r], 34.8 KB
  __shared__ __align__(16) float Xs[32 * 132];   // padded, 16.9 KB
  const float* Vm = Vt + (size_t)m * RR * DD;
  for (int t = tid; t < RR * DD; t += 256) {
    int r = t >> 7, c = t & 127;
    VtT[c * 68 + r] = Vm[t];
  }
  const float* Xm = X + ((size_t)m * SEQ + s0) * DD;
  for (int t = tid; t < 1024; t += 256) {  // 32 rows x 32 float4
    int s = t >> 5, c4 = t & 31;
    *(float4*)&Xs[s * 132 + 4 * c4] = *(const float4*)&Xm[(size_t)s * DD + 4 * c4];
  }
  __syncthreads();
  const int ti = tid >> 4;  // 0..15 -> rows 2ti, 2ti+1
  const int tj = tid & 15;  // cols 4tj..+3
  float acc[2][4] = {{0.f, 0.f, 0.f, 0.f}, {0.f, 0.f, 0.f, 0.f}};
#pragma unroll 4
  for (int k = 0; k < DD; ++k) {
    float a0 = Xs[(2 * ti) * 132 + k];
    float a1 = Xs[(2 * ti + 1) * 132 + k];
    float4 bv = *(float4*)&VtT[k * 68 + 4 * tj];
    acc[0][0] += a0 * bv.x; acc[0][1] += a0 * bv.y;
    acc[0][2] += a0 * bv.z; acc[0][3] += a0 * bv.w;
    acc[1][0] += a1 * bv.x; acc[1][1] += a1 * bv.y;
    acc[1][2] += a1 * bv.z; acc[1][3] += a1 * bv.w;
  }
  float* Wm = W + ((size_t)m * SEQ + s0) * RR;
#pragma unroll
  for (int d = 0; d < 2; ++d) {
    float4 v = make_float4(acc[d][0], acc[d][1], acc[d][2], acc[d][3]);
    *(float4*)&Wm[(size_t)(2 * ti + d) * RR + 4 * tj] = v;
  }
}

// ---------------- K5: out = W @ Vt  (2048x128 per matrix) ------------------
__global__ __launch_bounds__(256) void gemm2_k(const float* __restrict__ W,
                                               const float* __restrict__ Vt,
                                               float* __restrict__ out) {
  const int m = blockIdx.y;
  const int s0 = blockIdx.x * 32;
  const int tid = threadIdx.x;
  __shared__ __align__(16) float Vts[64 * 132];  // 33.8 KB
  __shared__ __align__(16) float Ws[32 * 68];    // 8.7 KB
  const float* Vm = Vt + (size_t)m * RR * DD;
  for (int t = tid; t < 2048; t += 256) {  // 64 rows x 32 float4
    int r = t >> 5, c4 = t & 31;
    *(float4*)&Vts[r * 132 + 4 * c4] = *(const float4*)&Vm[(size_t)r * DD + 4 * c4];
  }
  const float* Wm = W + ((size_t)m * SEQ + s0) * RR;
  for (int t = tid; t < 512; t += 256) {  // 32 rows x 16 float4
    int s = t >> 4, c4 = t & 15;
    *(float4*)&Ws[s * 68 + 4 * c4] = *(const float4*)&Wm[(size_t)s * RR + 4 * c4];
  }
  __syncthreads();
  const int ti = tid >> 5;  // 0..7 -> rows 4ti..+3
  const int tj = tid & 31;  // cols 4tj..+3
  float acc[4][4] = {{0.f,0.f,0.f,0.f},{0.f,0.f,0.f,0.f},
                     {0.f,0.f,0.f,0.f},{0.f,0.f,0.f,0.f}};
#pragma unroll 4
  for (int k = 0; k < RR; ++k) {
    float4 bv = *(float4*)&Vts[k * 132 + 4 * tj];
    float a0 = Ws[(4 * ti + 0) * 68 + k];
    float a1 = Ws[(4 * ti + 1) * 68 + k];
    float a2 = Ws[(4 * ti + 2) * 68 + k];
    float a3 = Ws[(4 * ti + 3) * 68 + k];
    acc[0][0] += a0 * bv.x; acc[0][1] += a0 * bv.y;
    acc[0][2] += a0 * bv.z; acc[0][3] += a0 * bv.w;
    acc[1][0] += a1 * bv.x; acc[1][1] += a1 * bv.y;
    acc[1][2] += a1 * bv.z; acc[1][3] += a1 * bv.w;
    acc[2][0] += a2 * bv.x; acc[2][1] += a2 * bv.y;
    acc[2][2] += a2 * bv.z; acc[2][3] += a2 * bv.w;
    acc[3][0] += a3 * bv.x; acc[3][1] += a3 * bv.y;
    acc[3][2] += a3 * bv.z; acc[3][3] += a3 * bv.w;
  }
  float* Om = out + ((size_t)m * SEQ + s0) * DD;
#pragma unroll
  for (int d = 0; d < 4; ++d) {
    float4 v = make_float4(acc[d][0], acc[d][1], acc[d][2], acc[d][3]);
    *(float4*)&Om[(size_t)(4 * ti + d) * DD + 4 * tj] = v;
  }
}

extern "C" void kernel_launch(void* const* d_in, const int* in_sizes, int n_in,
                              void* d_out, int out_size, void* d_ws, size_t ws_size,
                              hipStream_t stream) {
  (void)in_sizes; (void)n_in; (void)out_size; (void)ws_size;
  const float* X = (const float*)d_in[0];  // rank (d_in[1]) is fixed at 64
  float* out = (float*)d_out;
  char* ws = (char*)d_ws;
  float* G = (float*)ws;
  float* Vfull = (float*)(ws + OFF_VFULL);
  float* normg = (float*)(ws + OFF_NORM);
  float* Vt = (float*)(ws + OFF_VT);
  float* W = (float*)ws;  // overlays dead G/Vfull/normg

  gram_k<<<dim3(4, NM), 256, 0, stream>>>(X, G);
  jacobi1b_k<<<NM, 512, 0, stream>>>(G, Vfull, normg);
  select_k<<<NM, 128, 0, stream>>>(Vfull, normg, Vt);
  gemm1_k<<<dim3(SEQ / 32, NM), 256, 0, stream>>>(X, Vt, W);
  gemm2_k<<<dim3(SEQ / 32, NM), 256, 0, stream>>>(W, Vt, out);
}